// Round 7
// baseline (639.296 us; speedup 1.0000x reference)
//
#include <hip/hip_runtime.h>
#include <math.h>

// Matrix-Tree marginals: probs[b,i,j] = A[i,j]*(X[i-1,i-1] - (j>=1 ? X[j-1,i-1] : 0))
// X = inv(M) via blocked in-place Gauss-Jordan (4 panel steps of 64, SDD -> no pivoting).
// Round-7: (1) k_int+k_colP merged into k_upd using the in-place H = [G | Pinv] pivot-row
// panel: out[r][j] = (j in pivotcol ? 0 : M[r][j]) - F[r].H[:,j]  -- one pass, full-row
// coalesced RMW, 4 fewer launches, F read once. (2) k_gjrow: T14 prestage of R_old into
// registers before the serial GJ chain (loads drain under phase A).
// ws (doubles): M[B][256][256] | P[B][64][64] | mb[B] | nb[B](int) | Dg[B][256].

#define S 256
#define BB 256

__device__ __forceinline__ int rowmap(int lr, int kb) {   // local 0..191 -> global row/col skipping panel kb
    int rt = lr >> 6;
    int rb = rt + (rt >= kb ? 1 : 0);
    return rb * 64 + (lr & 63);
}

// ---------------- kernel 1a: dense max over each batch's full 256x256 score matrix ----------
// (marginals are exactly invariant to the stabilizer m, so global max is as good as masked max)
__global__ __launch_bounds__(256) void k_max(const float* __restrict__ sc,
                                             float* __restrict__ partial) {
    int b = blockIdx.y, rg = blockIdx.x;                 // 8 row-groups of 32 rows
    const float4* p4 = (const float4*)(sc + (size_t)b * S * S + rg * 8192);
    int tid = threadIdx.x;
    float4 v[8];
    #pragma unroll
    for (int it = 0; it < 8; ++it) v[it] = p4[tid + 256 * it];
    float m = -1e30f;
    #pragma unroll
    for (int it = 0; it < 8; ++it)
        m = fmaxf(m, fmaxf(fmaxf(v[it].x, v[it].y), fmaxf(v[it].z, v[it].w)));
    for (int off = 32; off > 0; off >>= 1) m = fmaxf(m, __shfl_down(m, off));
    __shared__ float sm[4];
    if ((tid & 63) == 0) sm[tid >> 6] = m;
    __syncthreads();
    if (tid == 0) partial[b * 8 + rg] = fmaxf(fmaxf(sm[0], sm[1]), fmaxf(sm[2], sm[3]));
}

// ---------------- kernel 1b: per-batch n (mask count) + combine partial maxima --------------
__global__ void k_n(const unsigned char* __restrict__ mk, const float* __restrict__ partial,
                    double* __restrict__ mb, int* __restrict__ nb) {
    int b = blockIdx.x, j = threadIdx.x;
    __shared__ int shc[4];

    const unsigned int* mw = (const unsigned int*)mk;    // sniff mask dtype
    unsigned int w0 = mw[0], w1 = mw[1];
    int mode = (w0 != 0u) ? 0 : ((w1 != 0u) ? 1 : 2);

    int c;
    if (mode == 0)      c = (mk[(size_t)b * S + j] != 0);
    else if (mode == 1) c = (((const int*)mk)[(size_t)b * S + j] != 0);
    else                c = (((const long long*)mk)[(size_t)b * S + j] != 0LL);

    int lane = j & 63, wid = j >> 6;
    int cs = c;
    for (int off = 32; off > 0; off >>= 1) cs += __shfl_down(cs, off);
    if (lane == 0) shc[wid] = cs;
    __syncthreads();
    if (j == 0) {
        nb[b] = shc[0] + shc[1] + shc[2] + shc[3];
        float mm = partial[b * 8];
        #pragma unroll
        for (int q = 1; q < 8; ++q) mm = fmaxf(mm, partial[b * 8 + q]);
        mb[b] = (double)mm;
    }
}

// ---------------- kernel 2: build padded M (f64, expf), 4 rows per block --------------------
__global__ __launch_bounds__(256) void k_build(const float* __restrict__ sc,
                                               const double* __restrict__ mb,
                                               const int* __restrict__ nb,
                                               double* __restrict__ Mg) {
    int b = blockIdx.y;
    int wid = threadIdx.x >> 6, lane = threadIdx.x & 63;
    int p = blockIdx.x * 4 + wid;
    int n = nb[b];
    double m = mb[b];
    __shared__ double se[4][260];
    double* Mrow = Mg + ((size_t)b * S + p) * S;
    bool act = (p < n);
    double ssum = 0.0;
    #pragma unroll
    for (int c4 = 0; c4 < 4; ++c4) {
        int j = lane + 64 * c4;
        double ev = 0.0;
        if (act && j <= n)
            ev = (double)expf((float)((double)sc[((size_t)b * S + (p + 1)) * S + j] - m));
        se[wid][j] = ev;
        ssum += ev;
    }
    for (int off = 32; off > 0; off >>= 1) ssum += __shfl_down(ssum, off);
    ssum = __shfl(ssum, 0);
    __syncthreads();                       // uniform: all 4 waves reach it
    #pragma unroll
    for (int c4 = 0; c4 < 4; ++c4) {
        int j = lane + 64 * c4;
        double v;
        if (act && j < n) v = ((j == p) ? ssum : 0.0) - se[wid][j + 1];
        else              v = (j == p) ? 1.0 : 0.0;
        Mrow[j] = v;
    }
}

// ---------------- kernel 3a: fused register-GJ inversion + row panel G = Pinv * R_old -------
// Phase A: thread (i = tid>>2, g = tid&3) owns row i, cols g*16.. of the diag block in 16 VGPRs.
// One barrier per pivot step (double-buffered pivot row/col broadcast). R_old is prestaged
// into registers BEFORE phase A (T14): its global latency drains under the serial GJ chain.
__global__ __launch_bounds__(256) void k_gjrow(double* __restrict__ Mg, double* __restrict__ Pg,
                                               int kb) {
    int b = blockIdx.x, tid = threadIdx.x;
    double* M = Mg + (size_t)b * S * S;
    double* P = Pg + (size_t)b * 4096;
    __shared__ double PT[64][66];        // PT[s][t] = Pinv[t][s]
    __shared__ double Rs[64][200];       // Rs[s][j] local cols (j in 0..191)
    __shared__ double rbuf[2][64];
    __shared__ double cbuf[2][64];

    int i = tid >> 2, g = tid & 3, c0 = g << 4;
    double c[16];
    #pragma unroll
    for (int u = 0; u < 16; ++u)
        c[u] = M[(size_t)(kb * 64 + i) * S + kb * 64 + c0 + u];

    // T14 prestage: R_old (pivot rows, non-pivot cols) -> registers; untouched by phase A.
    double rst[48];
    {
        int cidx = tid & 63;
        #pragma unroll
        for (int rep = 0; rep < 16; ++rep) {
            int r = rep * 4 + (tid >> 6);
            #pragma unroll
            for (int cc = 0; cc < 3; ++cc) {
                int j = cc * 64 + cidx;
                rst[rep * 3 + cc] = M[(size_t)(kb * 64 + r) * S + rowmap(j, kb)];
            }
        }
    }

    // prologue: publish step-0 buffers
    if (i == 0) {
        #pragma unroll
        for (int u = 0; u < 16; ++u) rbuf[0][c0 + u] = c[u];
    }
    if (g == 0) cbuf[0][i] = c[0];

    for (int kt = 0; kt < 4; ++kt) {
        #pragma unroll
        for (int ks = 0; ks < 16; ++ks) {
            int k = kt * 16 + ks;
            const int par = ks & 1;
            __syncthreads();
            double pv = rbuf[par][k];
            double f  = cbuf[par][i];
            double rk[16];
            #pragma unroll
            for (int m2 = 0; m2 < 8; ++m2) {
                double2 t = *(const double2*)&rbuf[par][c0 + 2 * m2];
                rk[2 * m2] = t.x; rk[2 * m2 + 1] = t.y;
            }
            double pivinv = 1.0 / pv;
            if (i == k) {
                #pragma unroll
                for (int u = 0; u < 16; ++u)
                    c[u] = ((g == kt) && (u == ks)) ? pivinv : c[u] * pivinv;
            } else {
                double gm = f * pivinv;
                #pragma unroll
                for (int u = 0; u < 16; ++u)
                    c[u] = ((g == kt) && (u == ks)) ? (-gm) : fma(-gm, rk[u], c[u]);
            }
            // publish buffers for step k+1 (no-ops harmlessly at k=63)
            if (i == k + 1) {
                #pragma unroll
                for (int u = 0; u < 16; ++u) rbuf[par ^ 1][c0 + u] = c[u];
            }
            if (ks < 15) { if (g == kt)     cbuf[par ^ 1][i] = c[ks + 1]; }
            else         { if (g == kt + 1) cbuf[par ^ 1][i] = c[0]; }
        }
    }
    // Pinv -> PT (LDS, transposed), P (global), M diag tile (its final value: H right part)
    #pragma unroll
    for (int u = 0; u < 16; ++u) {
        PT[c0 + u][i] = c[u];
        P[i * 64 + c0 + u] = c[u];
        M[(size_t)(kb * 64 + i) * S + kb * 64 + c0 + u] = c[u];
    }
    // write prestaged R_old into LDS
    {
        int cidx = tid & 63;
        #pragma unroll
        for (int rep = 0; rep < 16; ++rep) {
            int r = rep * 4 + (tid >> 6);
            #pragma unroll
            for (int cc = 0; cc < 3; ++cc)
                Rs[r][cc * 64 + cidx] = rst[rep * 3 + cc];
        }
    }
    __syncthreads();

    int tx = tid & 15, ty = tid >> 4;
    double2 acc[4][6];
    #pragma unroll
    for (int q = 0; q < 4; ++q)
        #pragma unroll
        for (int w = 0; w < 6; ++w) acc[q][w] = double2{0.0, 0.0};

    for (int s = 0; s < 64; ++s) {
        double2 p01 = *(const double2*)&PT[s][4 * ty];
        double2 p23 = *(const double2*)&PT[s][4 * ty + 2];
        #pragma unroll
        for (int w = 0; w < 6; ++w) {
            double2 r = *(const double2*)&Rs[s][2 * tx + 32 * w];
            acc[0][w].x = fma(p01.x, r.x, acc[0][w].x); acc[0][w].y = fma(p01.x, r.y, acc[0][w].y);
            acc[1][w].x = fma(p01.y, r.x, acc[1][w].x); acc[1][w].y = fma(p01.y, r.y, acc[1][w].y);
            acc[2][w].x = fma(p23.x, r.x, acc[2][w].x); acc[2][w].y = fma(p23.x, r.y, acc[2][w].y);
            acc[3][w].x = fma(p23.y, r.x, acc[3][w].x); acc[3][w].y = fma(p23.y, r.y, acc[3][w].y);
        }
    }
    // G written in place: pivot rows, non-pivot cols. Pivot rows' pivot cols hold Pinv.
    // => M[pivot rows][0..256) == H = [G | Pinv] consumed by k_upd.
    #pragma unroll
    for (int q = 0; q < 4; ++q) {
        size_t row = (size_t)(kb * 64 + 4 * ty + q) * S;
        #pragma unroll
        for (int w = 0; w < 6; ++w) {
            int j = 2 * tx + 32 * w;
            *(double2*)&M[row + rowmap(j, kb)] = acc[q][w];
        }
    }
}

// ---------------- kernel 3b: merged update  out = (pivotcol ? 0 : M) - F*H  -----------------
// One block per batch, 512 threads. 192 non-pivot rows x all 256 cols in two 96-row halves.
// H = M[pivot rows][:] in place ([G | Pinv]); F = block's own rows' old pivot-col values.
// Covers old k_int (interior: M - F*G) AND old k_colP (pivot col: -F*Pinv) in one pass.
__global__ __launch_bounds__(512) void k_upd(double* __restrict__ Mg, int kb) {
    int b = blockIdx.x;
    double* M = Mg + (size_t)b * S * S;
    int tid = threadIdx.x;
    __shared__ double Hs[16][258];       // Hs[kk][col] = H[ck*16+kk][col]
    __shared__ double FTs[16][98];       // FTs[kk][lr] = F[half*96+lr][ck*16+kk]
    int tx = tid & 31, ty = tid >> 5;    // ty 0..15 -> 6 rows each; tx 0..31 -> col pairs

    for (int half = 0; half < 2; ++half) {
        double2 acc[6][4];
        #pragma unroll
        for (int q = 0; q < 6; ++q)
            #pragma unroll
            for (int w = 0; w < 4; ++w) acc[q][w] = double2{0.0, 0.0};

        for (int ck = 0; ck < 4; ++ck) {
            __syncthreads();             // prior chunk's reads (and prior half's) done
            #pragma unroll
            for (int rep = 0; rep < 8; ++rep) {      // Hs: 16x256 = 4096 doubles
                int idx = rep * 512 + tid;
                int kk = idx >> 8, col = idx & 255;
                Hs[kk][col] = M[(size_t)(kb * 64 + ck * 16 + kk) * S + col];
            }
            #pragma unroll
            for (int rep = 0; rep < 3; ++rep) {      // FTs: 96x16 = 1536 doubles
                int idx = rep * 512 + tid;
                int kk = idx & 15, lr = idx >> 4;
                FTs[kk][lr] = M[(size_t)rowmap(half * 96 + lr, kb) * S + kb * 64 + ck * 16 + kk];
            }
            __syncthreads();
            for (int kk = 0; kk < 16; ++kk) {
                double2 f01 = *(const double2*)&FTs[kk][6 * ty];
                double2 f23 = *(const double2*)&FTs[kk][6 * ty + 2];
                double2 f45 = *(const double2*)&FTs[kk][6 * ty + 4];
                #pragma unroll
                for (int w = 0; w < 4; ++w) {
                    double2 h = *(const double2*)&Hs[kk][2 * tx + 64 * w];
                    acc[0][w].x = fma(f01.x, h.x, acc[0][w].x); acc[0][w].y = fma(f01.x, h.y, acc[0][w].y);
                    acc[1][w].x = fma(f01.y, h.x, acc[1][w].x); acc[1][w].y = fma(f01.y, h.y, acc[1][w].y);
                    acc[2][w].x = fma(f23.x, h.x, acc[2][w].x); acc[2][w].y = fma(f23.x, h.y, acc[2][w].y);
                    acc[3][w].x = fma(f23.y, h.x, acc[3][w].x); acc[3][w].y = fma(f23.y, h.y, acc[3][w].y);
                    acc[4][w].x = fma(f45.x, h.x, acc[4][w].x); acc[4][w].y = fma(f45.x, h.y, acc[4][w].y);
                    acc[5][w].x = fma(f45.y, h.x, acc[5][w].x); acc[5][w].y = fma(f45.y, h.y, acc[5][w].y);
                }
            }
        }
        // epilogue for this half: full-row coalesced RMW; pivot-col chunk (w==kb) base is 0.
        #pragma unroll
        for (int q = 0; q < 6; ++q) {
            size_t row = (size_t)rowmap(half * 96 + ty * 6 + q, kb) * S;
            #pragma unroll
            for (int w = 0; w < 4; ++w) {
                int j0 = 2 * tx + 64 * w;
                if (w == kb) {
                    *(double2*)&M[row + j0] = double2{-acc[q][w].x, -acc[q][w].y};
                } else {
                    double2 old = *(const double2*)&M[row + j0];
                    *(double2*)&M[row + j0] = double2{old.x - acc[q][w].x, old.y - acc[q][w].y};
                }
            }
        }
    }
}

// ---------------- kernel 4a: transpose X -> d_out (f32) at shifted positions + diag ---------
// XFs[b][i][j] := X[j-1][i-1] stored exactly where k_epi2 consumes it (i,j >= 1).
__global__ __launch_bounds__(256) void k_xt(const double* __restrict__ Mg,
                                            float* __restrict__ outF,
                                            double* __restrict__ Dg) {
    int b = blockIdx.y, t = blockIdx.x;
    int r = t & 3, c = t >> 2;
    const double* M = Mg + (size_t)b * S * S;
    __shared__ float L[64][65];
    int tid = threadIdx.x;
    int cc = tid & 63;
    #pragma unroll
    for (int rep = 0; rep < 16; ++rep) {
        int rr = rep * 4 + (tid >> 6);
        L[rr][cc] = (float)M[(size_t)(64 * r + rr) * S + 64 * c + cc];
    }
    if (r == c && tid < 64)
        Dg[(size_t)b * S + 64 * r + tid] = M[(size_t)(64 * r + tid) * S + 64 * r + tid];
    __syncthreads();
    int pp = tid & 63;
    #pragma unroll
    for (int rep = 0; rep < 16; ++rep) {
        int qq = rep * 4 + (tid >> 6);
        int orow = 64 * c + qq + 1, ocol = 64 * r + pp + 1;
        if (orow < 256 && ocol < 256)
            outF[((size_t)b * S + orow) * S + ocol] = L[pp][qq];   // = X[64r+pp][64c+qq]
    }
}

// ---------------- kernel 4b: elementwise in-place epilogue (float4) -------------------------
__global__ __launch_bounds__(256) void k_epi2(const float* __restrict__ sc,
                                              const double* __restrict__ Dg,
                                              const double* __restrict__ mb,
                                              const int* __restrict__ nb,
                                              float* __restrict__ out) {
    int b = blockIdx.y;
    int idx4 = blockIdx.x * 256 + threadIdx.x;    // 0..16383
    int i = idx4 >> 6;                            // row (wave-uniform)
    int jq = idx4 & 63;
    int n = nb[b];
    float m = (float)mb[b];
    size_t base = ((size_t)b * S + i) * S + 4 * jq;
    float4 xf = *(const float4*)(out + base);     // XFs[i][4jq..] = X[j-1][i-1]
    float4 s4 = *(const float4*)(sc + base);
    double dg = (i >= 1) ? Dg[(size_t)b * S + i - 1] : 0.0;
    float xfa[4] = {xf.x, xf.y, xf.z, xf.w};
    float sa[4]  = {s4.x, s4.y, s4.z, s4.w};
    float ra[4];
    #pragma unroll
    for (int comp = 0; comp < 4; ++comp) {
        int j = 4 * jq + comp;
        float v = 0.0f;
        if (i >= 1 && i <= n && j <= n) {
            double A = (double)expf(sa[comp] - m);
            double sub = (j >= 1) ? (double)xfa[comp] : 0.0;
            v = (float)(A * (dg - sub));
        }
        ra[comp] = v;
    }
    *(float4*)(out + base) = float4{ra[0], ra[1], ra[2], ra[3]};
}

// ---------------- launcher ----------------
extern "C" void kernel_launch(void* const* d_in, const int* in_sizes, int n_in,
                              void* d_out, int out_size, void* d_ws, size_t ws_size,
                              hipStream_t stream) {
    (void)in_sizes; (void)n_in; (void)out_size; (void)ws_size;
    const float* sc = (const float*)d_in[0];
    const unsigned char* mk = (const unsigned char*)d_in[1];
    double* ws = (double*)d_ws;

    double* M  = ws;                                 // B*256*256
    double* P  = M + (size_t)BB * S * S;             // B*64*64
    double* mb = P + (size_t)BB * 4096;              // B doubles
    int*    nb = (int*)(mb + BB);                    // B ints
    double* Dg = mb + 2 * BB;                        // B*256 doubles
    float*  partial = (float*)P;                     // aliases P (consumed before P written)
    float*  out = (float*)d_out;

    k_max<<<dim3(8, BB), 256, 0, stream>>>(sc, partial);
    k_n<<<BB, 256, 0, stream>>>(mk, partial, mb, nb);
    k_build<<<dim3(64, BB), 256, 0, stream>>>(sc, mb, nb, M);
    for (int kb = 0; kb < 4; ++kb) {
        k_gjrow<<<BB, 256, 0, stream>>>(M, P, kb);
        k_upd<<<BB, 512, 0, stream>>>(M, kb);
    }
    k_xt<<<dim3(16, BB), 256, 0, stream>>>(M, out, Dg);
    k_epi2<<<dim3(64, BB), 256, 0, stream>>>(sc, Dg, mb, nb, out);
}

// Round 8
// 570.735 us; speedup vs baseline: 1.1201x; 1.1201x over previous
//
#include <hip/hip_runtime.h>
#include <math.h>

// Matrix-Tree marginals: probs[b,i,j] = A[i,j]*(X[i-1,i-1] - (j>=1 ? X[j-1,i-1] : 0))
// X = inv(M) via blocked in-place Gauss-Jordan (4 panel steps of 64, SDD -> no pivoting).
// Round-8: ONE fused kernel per kb step. H = [G | Pinv] lives entirely in LDS:
//   phase 1: GJ-invert 64x64 diag block in registers (validated double-buffered rank-1 loop)
//   phase 2: G = Pinv * R_old (R staged in 8-row chunks), G+Pinv -> H (LDS), H -> M pivot rows
//   phase 3: update: interior RMW  M -= F*H ; pivot cols <- -F*Pinv   (two 96-row halves)
// Removes all H/P global round-trips and 4 launches vs round-7 (which measured VALUBusy 21%
// = fully serialized stage/compute at 1 block/CU).
// ws (doubles): M[B][256][256] | mb[B] | nb[B](int) | Dg[B][256]; partial aliases Dg.

#define S 256
#define BB 256

__device__ __forceinline__ int rowmap(int lr, int kb) {   // local 0..191 -> global row/col skipping panel kb
    int rt = lr >> 6;
    int rb = rt + (rt >= kb ? 1 : 0);
    return rb * 64 + (lr & 63);
}

// ---------------- kernel 1a: dense max over each batch's full 256x256 score matrix ----------
// (marginals are exactly invariant to the stabilizer m, so global max is as good as masked max)
__global__ __launch_bounds__(256) void k_max(const float* __restrict__ sc,
                                             float* __restrict__ partial) {
    int b = blockIdx.y, rg = blockIdx.x;                 // 8 row-groups of 32 rows
    const float4* p4 = (const float4*)(sc + (size_t)b * S * S + rg * 8192);
    int tid = threadIdx.x;
    float4 v[8];
    #pragma unroll
    for (int it = 0; it < 8; ++it) v[it] = p4[tid + 256 * it];
    float m = -1e30f;
    #pragma unroll
    for (int it = 0; it < 8; ++it)
        m = fmaxf(m, fmaxf(fmaxf(v[it].x, v[it].y), fmaxf(v[it].z, v[it].w)));
    for (int off = 32; off > 0; off >>= 1) m = fmaxf(m, __shfl_down(m, off));
    __shared__ float sm[4];
    if ((tid & 63) == 0) sm[tid >> 6] = m;
    __syncthreads();
    if (tid == 0) partial[b * 8 + rg] = fmaxf(fmaxf(sm[0], sm[1]), fmaxf(sm[2], sm[3]));
}

// ---------------- kernel 1b: per-batch n (mask count) + combine partial maxima --------------
__global__ void k_n(const unsigned char* __restrict__ mk, const float* __restrict__ partial,
                    double* __restrict__ mb, int* __restrict__ nb) {
    int b = blockIdx.x, j = threadIdx.x;
    __shared__ int shc[4];

    const unsigned int* mw = (const unsigned int*)mk;    // sniff mask dtype
    unsigned int w0 = mw[0], w1 = mw[1];
    int mode = (w0 != 0u) ? 0 : ((w1 != 0u) ? 1 : 2);

    int c;
    if (mode == 0)      c = (mk[(size_t)b * S + j] != 0);
    else if (mode == 1) c = (((const int*)mk)[(size_t)b * S + j] != 0);
    else                c = (((const long long*)mk)[(size_t)b * S + j] != 0LL);

    int lane = j & 63, wid = j >> 6;
    int cs = c;
    for (int off = 32; off > 0; off >>= 1) cs += __shfl_down(cs, off);
    if (lane == 0) shc[wid] = cs;
    __syncthreads();
    if (j == 0) {
        nb[b] = shc[0] + shc[1] + shc[2] + shc[3];
        float mm = partial[b * 8];
        #pragma unroll
        for (int q = 1; q < 8; ++q) mm = fmaxf(mm, partial[b * 8 + q]);
        mb[b] = (double)mm;
    }
}

// ---------------- kernel 2: build padded M (f64, expf), 4 rows per block --------------------
__global__ __launch_bounds__(256) void k_build(const float* __restrict__ sc,
                                               const double* __restrict__ mb,
                                               const int* __restrict__ nb,
                                               double* __restrict__ Mg) {
    int b = blockIdx.y;
    int wid = threadIdx.x >> 6, lane = threadIdx.x & 63;
    int p = blockIdx.x * 4 + wid;
    int n = nb[b];
    double m = mb[b];
    __shared__ double se[4][260];
    double* Mrow = Mg + ((size_t)b * S + p) * S;
    bool act = (p < n);
    double ssum = 0.0;
    #pragma unroll
    for (int c4 = 0; c4 < 4; ++c4) {
        int j = lane + 64 * c4;
        double ev = 0.0;
        if (act && j <= n)
            ev = (double)expf((float)((double)sc[((size_t)b * S + (p + 1)) * S + j] - m));
        se[wid][j] = ev;
        ssum += ev;
    }
    for (int off = 32; off > 0; off >>= 1) ssum += __shfl_down(ssum, off);
    ssum = __shfl(ssum, 0);
    __syncthreads();                       // uniform: all 4 waves reach it
    #pragma unroll
    for (int c4 = 0; c4 < 4; ++c4) {
        int j = lane + 64 * c4;
        double v;
        if (act && j < n) v = ((j == p) ? ssum : 0.0) - se[wid][j + 1];
        else              v = (j == p) ? 1.0 : 0.0;
        Mrow[j] = v;
    }
}

// ---------------- kernel 3: fused panel step (GJ + rowG + interior + colP) ------------------
__global__ __launch_bounds__(512) void k_step(double* __restrict__ Mg, int kb) {
    int b = blockIdx.x;
    double* M = Mg + (size_t)b * S * S;
    int tid = threadIdx.x;
    __shared__ double H[64 * 256];     // [G | Pinv] by GLOBAL column index, rows = pivot rows
    __shared__ double SCR[3104];       // union: GJ bufs (256) | PT(512)+Rc(1536) | FT 16x194(3104)

    // ---- phase 1: register GJ on the 64x64 diag block ----
    int i = tid >> 3, g = tid & 7, c0 = g << 3;   // row i, col group g (8 cols)
    double c[8];
    {
        const double* src = M + (size_t)(kb * 64 + i) * S + kb * 64 + c0;
        #pragma unroll
        for (int m2 = 0; m2 < 4; ++m2) {
            double2 t = *(const double2*)(src + 2 * m2);
            c[2 * m2] = t.x; c[2 * m2 + 1] = t.y;
        }
    }
    double* rbuf = SCR;          // [2][64]
    double* cbuf = SCR + 128;    // [2][64]
    if (i == 0) {
        #pragma unroll
        for (int u = 0; u < 8; ++u) rbuf[c0 + u] = c[u];
    }
    if (g == 0) cbuf[i] = c[0];
    for (int k = 0; k < 64; ++k) {
        int par = k & 1;
        __syncthreads();
        double pv = rbuf[par * 64 + k];
        double f  = cbuf[par * 64 + i];
        double rk[8];
        #pragma unroll
        for (int m2 = 0; m2 < 4; ++m2) {
            double2 t = *(const double2*)&rbuf[par * 64 + c0 + 2 * m2];
            rk[2 * m2] = t.x; rk[2 * m2 + 1] = t.y;
        }
        double pivinv = 1.0 / pv;
        int kg = k >> 3, ks = k & 7;
        if (i == k) {
            #pragma unroll
            for (int u = 0; u < 8; ++u)
                c[u] = ((g == kg) && (u == ks)) ? pivinv : c[u] * pivinv;
        } else {
            double gm = f * pivinv;
            #pragma unroll
            for (int u = 0; u < 8; ++u)
                c[u] = ((g == kg) && (u == ks)) ? (-gm) : fma(-gm, rk[u], c[u]);
        }
        int k1 = k + 1;
        if (k1 < 64) {
            if (i == k1) {
                #pragma unroll
                for (int u = 0; u < 8; ++u) rbuf[(par ^ 1) * 64 + c0 + u] = c[u];
            }
            if (g == (k1 >> 3)) cbuf[(par ^ 1) * 64 + i] = c[k1 & 7];
        }
    }
    __syncthreads();   // GJ done; SCR reusable. Threads hold Pinv[i][c0..c0+7] in c[].

    // ---- phase 2: G = Pinv * R_old  (8 chunks of 8 k-rows), G+Pinv -> H ----
    int tx = tid & 31, ty = tid >> 5;    // ty 0..15
    double* PT = SCR;                    // PT[sL][t] = Pinv[t][cs*8+sL]   [8][64]
    double* Rc = SCR + 512;              // Rc[sL][j] = R_old[cs*8+sL][j]  [8][192]
    double2 ga[4][3];
    #pragma unroll
    for (int r = 0; r < 4; ++r)
        #pragma unroll
        for (int q = 0; q < 3; ++q) ga[r][q] = double2{0.0, 0.0};

    for (int cs = 0; cs < 8; ++cs) {
        if (g == cs) {
            #pragma unroll
            for (int u = 0; u < 8; ++u) PT[u * 64 + i] = c[u];
        }
        #pragma unroll
        for (int rep = 0; rep < 3; ++rep) {
            int idx = rep * 512 + tid;
            int sL = idx / 192, jj = idx - sL * 192;
            Rc[sL * 192 + jj] = M[(size_t)(kb * 64 + cs * 8 + sL) * S + rowmap(jj, kb)];
        }
        __syncthreads();
        #pragma unroll
        for (int sL = 0; sL < 8; ++sL) {
            double2 p01 = *(const double2*)&PT[sL * 64 + 4 * ty];
            double2 p23 = *(const double2*)&PT[sL * 64 + 4 * ty + 2];
            double2 r0 = *(const double2*)&Rc[sL * 192 + 2 * tx];
            double2 r1 = *(const double2*)&Rc[sL * 192 + 2 * tx + 64];
            double2 r2 = *(const double2*)&Rc[sL * 192 + 2 * tx + 128];
            ga[0][0].x = fma(p01.x, r0.x, ga[0][0].x); ga[0][0].y = fma(p01.x, r0.y, ga[0][0].y);
            ga[0][1].x = fma(p01.x, r1.x, ga[0][1].x); ga[0][1].y = fma(p01.x, r1.y, ga[0][1].y);
            ga[0][2].x = fma(p01.x, r2.x, ga[0][2].x); ga[0][2].y = fma(p01.x, r2.y, ga[0][2].y);
            ga[1][0].x = fma(p01.y, r0.x, ga[1][0].x); ga[1][0].y = fma(p01.y, r0.y, ga[1][0].y);
            ga[1][1].x = fma(p01.y, r1.x, ga[1][1].x); ga[1][1].y = fma(p01.y, r1.y, ga[1][1].y);
            ga[1][2].x = fma(p01.y, r2.x, ga[1][2].x); ga[1][2].y = fma(p01.y, r2.y, ga[1][2].y);
            ga[2][0].x = fma(p23.x, r0.x, ga[2][0].x); ga[2][0].y = fma(p23.x, r0.y, ga[2][0].y);
            ga[2][1].x = fma(p23.x, r1.x, ga[2][1].x); ga[2][1].y = fma(p23.x, r1.y, ga[2][1].y);
            ga[2][2].x = fma(p23.x, r2.x, ga[2][2].x); ga[2][2].y = fma(p23.x, r2.y, ga[2][2].y);
            ga[3][0].x = fma(p23.y, r0.x, ga[3][0].x); ga[3][0].y = fma(p23.y, r0.y, ga[3][0].y);
            ga[3][1].x = fma(p23.y, r1.x, ga[3][1].x); ga[3][1].y = fma(p23.y, r1.y, ga[3][1].y);
            ga[3][2].x = fma(p23.y, r2.x, ga[3][2].x); ga[3][2].y = fma(p23.y, r2.y, ga[3][2].y);
        }
        __syncthreads();                 // inner reads done before next chunk restages SCR
    }
    // G -> H (global-column indexing), Pinv -> H pivot cols
    #pragma unroll
    for (int r = 0; r < 4; ++r)
        #pragma unroll
        for (int q = 0; q < 3; ++q) {
            int col = rowmap(2 * tx + 64 * q, kb);
            *(double2*)&H[(4 * ty + r) * 256 + col] = ga[r][q];
        }
    #pragma unroll
    for (int u = 0; u < 8; ++u) H[i * 256 + kb * 64 + c0 + u] = c[u];
    __syncthreads();                     // H complete

    // H -> M pivot rows (early: global writes drain under the update phase)
    #pragma unroll
    for (int rep = 0; rep < 16; ++rep) {
        int idx = rep * 512 + tid;
        int row = idx >> 7, col2 = idx & 127;
        *(double2*)&M[(size_t)(kb * 64 + row) * S + 2 * col2] =
            *(const double2*)&H[row * 256 + 2 * col2];
    }

    // ---- phase 3: update. interior RMW M -= F*H ; pivot cols <- -F*Pinv. Two 96-row halves.
    double* FT = SCR;                    // FT[kk][lr] = F[half*96+lr][ck*16+kk]  [16][194]
    for (int half = 0; half < 2; ++half) {
        double2 acc[6][4];
        #pragma unroll
        for (int q = 0; q < 6; ++q)
            #pragma unroll
            for (int w = 0; w < 4; ++w) acc[q][w] = double2{0.0, 0.0};

        for (int ck = 0; ck < 4; ++ck) {
            __syncthreads();             // prior SCR reads done
            #pragma unroll
            for (int rep = 0; rep < 3; ++rep) {
                int idx = rep * 512 + tid;
                int kk = idx & 15, lr = idx >> 4;    // lr 0..95
                FT[kk * 194 + lr] =
                    M[(size_t)rowmap(half * 96 + lr, kb) * S + kb * 64 + ck * 16 + kk];
            }
            __syncthreads();
            for (int kk = 0; kk < 16; ++kk) {
                int kr = ck * 16 + kk;
                double2 f01 = *(const double2*)&FT[kk * 194 + 6 * ty];
                double2 f23 = *(const double2*)&FT[kk * 194 + 6 * ty + 2];
                double2 f45 = *(const double2*)&FT[kk * 194 + 6 * ty + 4];
                #pragma unroll
                for (int w = 0; w < 4; ++w) {
                    double2 h = *(const double2*)&H[kr * 256 + 2 * tx + 64 * w];
                    acc[0][w].x = fma(f01.x, h.x, acc[0][w].x); acc[0][w].y = fma(f01.x, h.y, acc[0][w].y);
                    acc[1][w].x = fma(f01.y, h.x, acc[1][w].x); acc[1][w].y = fma(f01.y, h.y, acc[1][w].y);
                    acc[2][w].x = fma(f23.x, h.x, acc[2][w].x); acc[2][w].y = fma(f23.x, h.y, acc[2][w].y);
                    acc[3][w].x = fma(f23.y, h.x, acc[3][w].x); acc[3][w].y = fma(f23.y, h.y, acc[3][w].y);
                    acc[4][w].x = fma(f45.x, h.x, acc[4][w].x); acc[4][w].y = fma(f45.x, h.y, acc[4][w].y);
                    acc[5][w].x = fma(f45.y, h.x, acc[5][w].x); acc[5][w].y = fma(f45.y, h.y, acc[5][w].y);
                }
            }
        }
        // epilogue: own rows only (all F reads for this half are complete)
        #pragma unroll
        for (int q = 0; q < 6; ++q) {
            size_t row = (size_t)rowmap(half * 96 + 6 * ty + q, kb) * S;
            #pragma unroll
            for (int w = 0; w < 4; ++w) {
                int j0 = 2 * tx + 64 * w;
                if (w == kb) {
                    *(double2*)&M[row + j0] = double2{-acc[q][w].x, -acc[q][w].y};
                } else {
                    double2 old = *(const double2*)&M[row + j0];
                    *(double2*)&M[row + j0] = double2{old.x - acc[q][w].x, old.y - acc[q][w].y};
                }
            }
        }
    }
}

// ---------------- kernel 4a: transpose X -> d_out (f32) at shifted positions + diag ---------
// XFs[b][i][j] := X[j-1][i-1] stored exactly where k_epi2 consumes it (i,j >= 1).
__global__ __launch_bounds__(256) void k_xt(const double* __restrict__ Mg,
                                            float* __restrict__ outF,
                                            double* __restrict__ Dg) {
    int b = blockIdx.y, t = blockIdx.x;
    int r = t & 3, c = t >> 2;
    const double* M = Mg + (size_t)b * S * S;
    __shared__ float L[64][65];
    int tid = threadIdx.x;
    int cc = tid & 63;
    #pragma unroll
    for (int rep = 0; rep < 16; ++rep) {
        int rr = rep * 4 + (tid >> 6);
        L[rr][cc] = (float)M[(size_t)(64 * r + rr) * S + 64 * c + cc];
    }
    if (r == c && tid < 64)
        Dg[(size_t)b * S + 64 * r + tid] = M[(size_t)(64 * r + tid) * S + 64 * r + tid];
    __syncthreads();
    int pp = tid & 63;
    #pragma unroll
    for (int rep = 0; rep < 16; ++rep) {
        int qq = rep * 4 + (tid >> 6);
        int orow = 64 * c + qq + 1, ocol = 64 * r + pp + 1;
        if (orow < 256 && ocol < 256)
            outF[((size_t)b * S + orow) * S + ocol] = L[pp][qq];   // = X[64r+pp][64c+qq]
    }
}

// ---------------- kernel 4b: elementwise in-place epilogue (float4) -------------------------
__global__ __launch_bounds__(256) void k_epi2(const float* __restrict__ sc,
                                              const double* __restrict__ Dg,
                                              const double* __restrict__ mb,
                                              const int* __restrict__ nb,
                                              float* __restrict__ out) {
    int b = blockIdx.y;
    int idx4 = blockIdx.x * 256 + threadIdx.x;    // 0..16383
    int i = idx4 >> 6;                            // row (wave-uniform)
    int jq = idx4 & 63;
    int n = nb[b];
    float m = (float)mb[b];
    size_t base = ((size_t)b * S + i) * S + 4 * jq;
    float4 xf = *(const float4*)(out + base);     // XFs[i][4jq..] = X[j-1][i-1]
    float4 s4 = *(const float4*)(sc + base);
    double dg = (i >= 1) ? Dg[(size_t)b * S + i - 1] : 0.0;
    float xfa[4] = {xf.x, xf.y, xf.z, xf.w};
    float sa[4]  = {s4.x, s4.y, s4.z, s4.w};
    float ra[4];
    #pragma unroll
    for (int comp = 0; comp < 4; ++comp) {
        int j = 4 * jq + comp;
        float v = 0.0f;
        if (i >= 1 && i <= n && j <= n) {
            double A = (double)expf(sa[comp] - m);
            double sub = (j >= 1) ? (double)xfa[comp] : 0.0;
            v = (float)(A * (dg - sub));
        }
        ra[comp] = v;
    }
    *(float4*)(out + base) = float4{ra[0], ra[1], ra[2], ra[3]};
}

// ---------------- launcher ----------------
extern "C" void kernel_launch(void* const* d_in, const int* in_sizes, int n_in,
                              void* d_out, int out_size, void* d_ws, size_t ws_size,
                              hipStream_t stream) {
    (void)in_sizes; (void)n_in; (void)out_size; (void)ws_size;
    const float* sc = (const float*)d_in[0];
    const unsigned char* mk = (const unsigned char*)d_in[1];
    double* ws = (double*)d_ws;

    double* M  = ws;                                 // B*256*256
    double* mb = M + (size_t)BB * S * S;             // B doubles
    int*    nb = (int*)(mb + BB);                    // B ints
    double* Dg = mb + 2 * BB;                        // B*256 doubles
    float*  partial = (float*)Dg;                    // aliases Dg (consumed before Dg written)
    float*  out = (float*)d_out;

    k_max<<<dim3(8, BB), 256, 0, stream>>>(sc, partial);
    k_n<<<BB, 256, 0, stream>>>(mk, partial, mb, nb);
    k_build<<<dim3(64, BB), 256, 0, stream>>>(sc, mb, nb, M);
    for (int kb = 0; kb < 4; ++kb)
        k_step<<<BB, 512, 0, stream>>>(M, kb);
    k_xt<<<dim3(16, BB), 256, 0, stream>>>(M, out, Dg);
    k_epi2<<<dim3(64, BB), 256, 0, stream>>>(sc, Dg, mb, nb, out);
}